// Round 11
// baseline (182.234 us; speedup 1.0000x reference)
//
#include <hip/hip_runtime.h>
#include <stdint.h>

typedef __attribute__((ext_vector_type(8))) short short8;
typedef __attribute__((ext_vector_type(8))) __bf16 bf16x8v;
typedef __attribute__((ext_vector_type(4))) float f32x4;

#define GLOBAL_AS __attribute__((address_space(1)))
#define LDS_AS __attribute__((address_space(3)))

__device__ __forceinline__ void gl2lds16(const void* g, void* l) {
  __builtin_amdgcn_global_load_lds((const GLOBAL_AS void*)g, (LDS_AS void*)l, 16, 0, 0);
}

__device__ __forceinline__ unsigned short f2bf(float x) {
  unsigned int u = __builtin_bit_cast(unsigned int, x);
  return (unsigned short)((u + 0x7fffu + ((u >> 16) & 1u)) >> 16);
}

__device__ __forceinline__ float bf2f(unsigned short u) {
  unsigned int v = (unsigned int)u << 16;
  return __builtin_bit_cast(float, v);
}

__device__ __forceinline__ unsigned cvtpk(float lo, float hi) {
  unsigned r;
  asm volatile("v_cvt_pk_bf16_f32 %0, %1, %2" : "=v"(r) : "v"(lo), "v"(hi));
  return r;
}

__device__ __forceinline__ short8 ldv8(const unsigned short* p) {
  return *(const short8*)p;
}

// --- MFMA wrapper: SFINAE-hedged against builtin operand type (short8 vs v8bf16) ---
template <typename T>
__device__ __forceinline__ auto mfma_impl(T a, T b, f32x4 c, int)
    -> decltype(__builtin_amdgcn_mfma_f32_16x16x32_bf16(a, b, c, 0, 0, 0)) {
  return __builtin_amdgcn_mfma_f32_16x16x32_bf16(a, b, c, 0, 0, 0);
}
template <typename T>
__device__ __forceinline__ f32x4 mfma_impl(T a, T b, f32x4 c, long) {
  bf16x8v aa = __builtin_bit_cast(bf16x8v, a);
  bf16x8v bb = __builtin_bit_cast(bf16x8v, b);
  return __builtin_amdgcn_mfma_f32_16x16x32_bf16(aa, bb, c, 0, 0, 0);
}
__device__ __forceinline__ f32x4 mfma16(short8 a, short8 b, f32x4 c) {
  return mfma_impl(a, b, c, 0);
}

// ---------------- cast fp32 -> bf16 (vectorized) ----------------
__global__ __launch_bounds__(256) void cast_bf16_kernel(const float* __restrict__ X,
                                                        unsigned short* __restrict__ Y,
                                                        int n4) {
  int i = blockIdx.x * 256 + threadIdx.x;
  if (i >= n4) return;
  const float4 v = ((const float4*)X)[i];
  unsigned long long pk = (unsigned long long)f2bf(v.x)
                        | ((unsigned long long)f2bf(v.y) << 16)
                        | ((unsigned long long)f2bf(v.z) << 32)
                        | ((unsigned long long)f2bf(v.w) << 48);
  ((unsigned long long*)Y)[i] = pk;
}

// ---------------- transpose + cast: W[K][N] fp32 -> Wt[N][K] bf16 ----------------
__global__ __launch_bounds__(256) void transpose_cast_kernel(const float* __restrict__ W,
                                                             unsigned short* __restrict__ Wt,
                                                             int Kd, int Nd) {
  __shared__ unsigned short tile[32][33];
  const int n0 = blockIdx.x * 32, k0 = blockIdx.y * 32;
  const int tx = threadIdx.x & 31, ty = threadIdx.x >> 5;  // 32x8
  #pragma unroll
  for (int i = 0; i < 4; ++i)
    tile[ty + i * 8][tx] = f2bf(W[(long)(k0 + ty + i * 8) * Nd + n0 + tx]);
  __syncthreads();
  #pragma unroll
  for (int i = 0; i < 4; ++i)
    Wt[(long)(n0 + ty + i * 8) * Kd + k0 + tx] = tile[tx][ty + i * 8];
}

// ---------------- GEMM: C[M,N] = A[M,K] @ Wt[N,K]^T + bias ----------------
// 128x128 tile, BK=32, TRIPLE-buffered with counted vmcnt(4).
// XCD-aware 1D block decode. MODE 0: QKV scatter; MODE 1: fp32 out.
template <int MODE>
__global__ __launch_bounds__(256, 3) void gemm_kernel(
    const unsigned short* __restrict__ A,   // [M][K] bf16
    const unsigned short* __restrict__ Wt,  // [N][K] bf16
    const float* __restrict__ bias,         // [N]
    float* __restrict__ Cout,               // MODE1
    unsigned short* __restrict__ Qb,
    unsigned short* __restrict__ Kb,
    unsigned short* __restrict__ Vt,
    int M, int N, int K) {
  __shared__ __align__(16) unsigned short Asm[3][128 * 32];
  __shared__ __align__(16) unsigned short Bsm[3][128 * 32];
  const int tid = threadIdx.x;
  const int w = tid >> 6, l = tid & 63;

  const int bid = blockIdx.x;
  const int xcd = bid & 7, tt = bid >> 3;
  int xb, yb;
  if (MODE == 0) {
    xb = (xcd & 1) * 12 + tt % 12;   // 24 n-blocks
    yb = (xcd >> 1) * 16 + tt / 12;  // 64 m-blocks
  } else {
    xb = tt & 7;                     // 8 n-blocks
    yb = xcd * 8 + (tt >> 3);        // 64 m-blocks
  }
  const int m0 = yb * 128, n0 = xb * 128;

  const int wr = (w >> 1) * 64, wc = (w & 1) * 64;
  const int laneRow = l & 15, laneG = l >> 4;

  const f32x4 z4 = {0.f, 0.f, 0.f, 0.f};
  f32x4 acc[4][4];
  #pragma unroll
  for (int m = 0; m < 4; ++m)
    #pragma unroll
    for (int n = 0; n < 4; ++n) acc[m][n] = z4;

  const int srow = tid >> 2;
  const int scol = (tid & 3) * 8;
  const unsigned short* Ag = A + (long)(m0 + srow) * K + scol;
  const unsigned short* Bg = Wt + (long)(n0 + srow) * K + scol;

  const int aoff = (wr + laneRow) * 32 + laneG * 8;
  const int boff = (wc + laneRow) * 32 + laneG * 8;

  auto STAGE = [&](int buf, int kt) {
    gl2lds16(Ag + kt, &Asm[buf][w * 512]);
    gl2lds16(Ag + (long)64 * K + kt, &Asm[buf][2048 + w * 512]);
    gl2lds16(Bg + kt, &Bsm[buf][w * 512]);
    gl2lds16(Bg + (long)64 * K + kt, &Bsm[buf][2048 + w * 512]);
  };

  const int NT = K >> 5;
  STAGE(0, 0);
  STAGE(1, 32);
  asm volatile("s_waitcnt vmcnt(4)" ::: "memory");  // tile0 ready; tile1 in flight
  asm volatile("s_barrier" ::: "memory");

  int cur = 0, sb = 2;
  for (int t = 0; t < NT; ++t) {
    if (t + 2 < NT) STAGE(sb, (t + 2) * 32);
    short8 af[4], bfr[4];
    #pragma unroll
    for (int m = 0; m < 4; ++m) af[m] = ldv8(&Asm[cur][aoff + m * 512]);
    #pragma unroll
    for (int n = 0; n < 4; ++n) bfr[n] = ldv8(&Bsm[cur][boff + n * 512]);
    __builtin_amdgcn_s_setprio(1);
    #pragma unroll
    for (int m = 0; m < 4; ++m)
      #pragma unroll
      for (int n = 0; n < 4; ++n)
        acc[m][n] = mfma16(af[m], bfr[n], acc[m][n]);
    __builtin_amdgcn_s_setprio(0);
    if (t + 2 < NT) {
      asm volatile("s_waitcnt vmcnt(4)" ::: "memory");
    } else {
      asm volatile("s_waitcnt vmcnt(0)" ::: "memory");
    }
    asm volatile("s_barrier" ::: "memory");
    cur = (cur == 2) ? 0 : cur + 1;
    sb = (sb == 2) ? 0 : sb + 1;
  }

  if (MODE == 0 && n0 >= 2048) {
    #pragma unroll
    for (int m = 0; m < 4; ++m) {
      const int row_base = m0 + wr + m * 16 + laneG * 4;
      #pragma unroll
      for (int n = 0; n < 4; ++n) {
        const int col = n0 + wc + n * 16 + laneRow;
        const float bv = bias[col];
        const int d = col & 1023;
        const int h = d >> 6, e = d & 63;
        const int bb = row_base >> 11, s = row_base & 2047;
        unsigned long long pk = (unsigned long long)f2bf(acc[m][n][0] + bv)
                              | ((unsigned long long)f2bf(acc[m][n][1] + bv) << 16)
                              | ((unsigned long long)f2bf(acc[m][n][2] + bv) << 32)
                              | ((unsigned long long)f2bf(acc[m][n][3] + bv) << 48);
        *(unsigned long long*)(Vt + ((long)((bb * 16 + h) * 64 + e)) * 2048 + s) = pk;
      }
    }
    return;
  }

  // LDS-bounce epilogue: per-wave 16x68 f32 region, coalesced 16B stores
  float* ep = (float*)&Asm[0][0] + w * 1088;
  const int c0 = (l & 7) * 8;
  const int rrow = l >> 3;
  const int colg0 = n0 + wc + c0;
  float bv[8];
  #pragma unroll
  for (int j = 0; j < 8; ++j) bv[j] = bias[colg0 + j];
  unsigned short* Tqk = (colg0 >> 10) ? Kb : Qb;
  const int hh = (colg0 & 1023) >> 6, e0 = colg0 & 63;

  #pragma unroll
  for (int m = 0; m < 4; ++m) {
    asm volatile("s_waitcnt lgkmcnt(0)" ::: "memory");
    #pragma unroll
    for (int n = 0; n < 4; ++n)
      #pragma unroll
      for (int r = 0; r < 4; ++r)
        ep[(laneG * 4 + r) * 68 + n * 16 + laneRow] = acc[m][n][r];
    asm volatile("s_waitcnt lgkmcnt(0)" ::: "memory");
    #pragma unroll
    for (int j = 0; j < 2; ++j) {
      const int row = rrow + j * 8;
      f32x4 va = *(const f32x4*)&ep[row * 68 + c0];
      f32x4 vb = *(const f32x4*)&ep[row * 68 + c0 + 4];
      va[0] += bv[0]; va[1] += bv[1]; va[2] += bv[2]; va[3] += bv[3];
      vb[0] += bv[4]; vb[1] += bv[5]; vb[2] += bv[6]; vb[3] += bv[7];
      const int row_g = m0 + wr + m * 16 + row;
      if (MODE == 1) {
        *(f32x4*)&Cout[(long)row_g * N + colg0] = va;
        *(f32x4*)&Cout[(long)row_g * N + colg0 + 4] = vb;
      } else {
        uint4 pk;
        pk.x = cvtpk(va[0], va[1]);
        pk.y = cvtpk(va[2], va[3]);
        pk.z = cvtpk(vb[0], vb[1]);
        pk.w = cvtpk(vb[2], vb[3]);
        const int bb = row_g >> 11, s = row_g & 2047;
        *(uint4*)(Tqk + ((long)(bb * 16 + hh) * 2048 + s) * 64 + e0) = pk;
      }
    }
  }
}

// ---------------- flash attention (causal), bf16 MFMA ----------------
// QBLK=128, 8 waves. Paired tiles px/(15-px), XCD-aware head grouping.
// SWAPPED QK^T -> S^T per lane; P via cvt_pk + b64 writes; no max-shift;
// rowsum via mfma(P, ones). TRIPLE-buffered K/V with counted vmcnt(2):
// stage tile t+2 at loop top; boundary vmcnt(2) drains exactly t+1's two
// loads and keeps t+2's in flight across the barrier (no drain-to-0).
__global__ __launch_bounds__(512) void attn_kernel(
    const unsigned short* __restrict__ Qb,   // [B*H][2048][64]
    const unsigned short* __restrict__ Kb,   // [B*H][2048][64]
    const unsigned short* __restrict__ Vt,   // [B*H][64][2048]
    unsigned short* __restrict__ Ao) {       // [B*2048][1024]
  __shared__ __align__(16) unsigned short Ksm[3][64 * 64];
  __shared__ __align__(16) unsigned short Vsm[3][64 * 64];
  __shared__ __align__(16) unsigned short Psm[8][16][72];

  const int tid = threadIdx.x;
  const int w = tid >> 6, l = tid & 63;
  const int bid = blockIdx.x;
  const int px = bid >> 6;                              // 0..7
  const int y = ((bid & 7) << 3) | ((bid >> 3) & 7);    // same-XCD head grouping
  const int laneRow = l & 15, g = l >> 4;
  const unsigned short* Qh = Qb + (long)y * (2048 * 64);
  const unsigned short* Kh = Kb + (long)y * (2048 * 64);
  const unsigned short* Vh = Vt + (long)y * (64 * 2048);

  const int srow = tid >> 3;
  const int sxor = ((tid & 7) ^ (srow & 7)) * 8;
  const int b = y >> 4, h = y & 15;
  const f32x4 z4 = {0.f, 0.f, 0.f, 0.f};
  short8 ones8;
  #pragma unroll
  for (int j = 0; j < 8; ++j) ones8[j] = (short)0x3F80;

  auto STAGE = [&](int buf, int kt) {
    gl2lds16(Kh + (long)kt * 4096 + srow * 64 + sxor, &Ksm[buf][w * 512]);
    gl2lds16(Vh + kt * 64 + (long)srow * 2048 + sxor, &Vsm[buf][w * 512]);
  };

  for (int pass = 0; pass < 2; ++pass) {
    const int x = pass ? (15 - px) : px;
    const int q0 = x * 128;
    const int qlo = w * 16;

    const float QS = 0.18033688011112042f;
    short8 qf[2];
    {
      short8 r0 = ldv8(Qh + (q0 + qlo + laneRow) * 64 + g * 8);
      short8 r1 = ldv8(Qh + (q0 + qlo + laneRow) * 64 + 32 + g * 8);
      #pragma unroll
      for (int j = 0; j < 8; ++j) {
        qf[0][j] = (short)f2bf(bf2f((unsigned short)r0[j]) * QS);
        qf[1][j] = (short)f2bf(bf2f((unsigned short)r1[j]) * QS);
      }
    }

    float lr[4] = {0.f, 0.f, 0.f, 0.f};
    f32x4 o[4];
    #pragma unroll
    for (int i = 0; i < 4; ++i) o[i] = z4;

    const int nkt = 2 * x + 2;  // always >= 2
    STAGE(0, 0);
    STAGE(1, 1);
    asm volatile("s_waitcnt vmcnt(2)" ::: "memory");  // tile0 ready; tile1 in flight
    __builtin_amdgcn_s_barrier();

    int cur = 0, sb = 2;
    for (int kt = 0; kt < nkt; ++kt) {
      if (kt + 2 < nkt) STAGE(sb, kt + 2);

      const int keybase = kt * 64 - q0;
      const bool fullskip = keybase > qlo + 15;

      if (!fullskip) {
        f32x4 sc[4];
        __builtin_amdgcn_s_setprio(1);
        #pragma unroll
        for (int n = 0; n < 4; ++n) {
          const int krow = n * 16 + laneRow;
          short8 b0 = ldv8(&Ksm[cur][krow * 64 + ((g ^ (krow & 7)) * 8)]);
          short8 b1 = ldv8(&Ksm[cur][krow * 64 + (((g + 4) ^ (krow & 7)) * 8)]);
          f32x4 a = mfma16(b0, qf[0], z4);
          sc[n] = mfma16(b1, qf[1], a);
        }
        __builtin_amdgcn_s_setprio(0);

        if (keybase + 63 > qlo) {
          #pragma unroll
          for (int n = 0; n < 4; ++n) {
            const int keyb = keybase + n * 16 + g * 4;
            #pragma unroll
            for (int r = 0; r < 4; ++r)
              if (keyb + r > qlo + laneRow) sc[n][r] = -1e9f;
          }
        }

        #pragma unroll
        for (int n = 0; n < 4; ++n)
          #pragma unroll
          for (int r = 0; r < 4; ++r)
            sc[n][r] = exp2f(sc[n][r]);

        #pragma unroll
        for (int n = 0; n < 4; ++n) {
          uint2 pk;
          pk.x = cvtpk(sc[n][0], sc[n][1]);
          pk.y = cvtpk(sc[n][2], sc[n][3]);
          *(uint2*)&Psm[w][laneRow][n * 16 + g * 4] = pk;
        }
        asm volatile("s_waitcnt lgkmcnt(0)" ::: "memory");

        f32x4 rs = z4;
        #pragma unroll
        for (int kk = 0; kk < 2; ++kk) {
          short8 pf = ldv8(&Psm[w][laneRow][kk * 32 + g * 8]);
          __builtin_amdgcn_s_setprio(1);
          #pragma unroll
          for (int n2 = 0; n2 < 4; ++n2) {
            const int vrow = n2 * 16 + laneRow;
            short8 vf = ldv8(&Vsm[cur][vrow * 64 + (((g + kk * 4) ^ (vrow & 7)) * 8)]);
            o[n2] = mfma16(pf, vf, o[n2]);
          }
          rs = mfma16(pf, ones8, rs);
          __builtin_amdgcn_s_setprio(0);
        }
        #pragma unroll
        for (int r = 0; r < 4; ++r) lr[r] += rs[r];
      }

      // boundary: tile kt+1 must be resident; kt+2's loads stay in flight
      if (kt + 2 < nkt) {
        asm volatile("s_waitcnt vmcnt(2)" ::: "memory");
      } else {
        asm volatile("s_waitcnt vmcnt(0)" ::: "memory");
      }
      __builtin_amdgcn_s_barrier();
      cur = (cur == 2) ? 0 : cur + 1;
      sb = (sb == 2) ? 0 : sb + 1;
    }

    #pragma unroll
    for (int n2 = 0; n2 < 4; ++n2) {
      #pragma unroll
      for (int r = 0; r < 4; ++r) {
        float v = o[n2][r] / lr[r];
        long row = (long)b * 2048 + q0 + qlo + g * 4 + r;
        Ao[row * 1024 + h * 64 + n2 * 16 + laneRow] = f2bf(v);
      }
    }
  }
}

// ---------------- launch ----------------
extern "C" void kernel_launch(void* const* d_in, const int* in_sizes, int n_in,
                              void* d_out, int out_size, void* d_ws, size_t ws_size,
                              hipStream_t stream) {
  const float* hs = (const float*)d_in[0];      // [4,2048,1024]
  const float* W_attn = (const float*)d_in[1];  // [1024,3072]
  const float* b_attn = (const float*)d_in[2];  // [3072]
  const float* W_proj = (const float*)d_in[3];  // [1024,1024]
  const float* b_proj = (const float*)d_in[4];  // [1024]
  float* out = (float*)d_out;

  const size_t SZ_HS = 16777216;  // 8192*1024*2
  const size_t SZ_WA = 6291456;   // 3072*1024*2
  const size_t SZ_WP = 2097152;   // 1024*1024*2
  const size_t SZ_T = 16777216;   // Q / K / Vt / Ao each
  if (ws_size < SZ_HS + SZ_WA + SZ_WP + 4 * SZ_T) return;

  char* p = (char*)d_ws;
  unsigned short* hs_bf = (unsigned short*)p; p += SZ_HS;
  unsigned short* WtA = (unsigned short*)p;   p += SZ_WA;
  unsigned short* WtP = (unsigned short*)p;   p += SZ_WP;
  unsigned short* Qb = (unsigned short*)p;    p += SZ_T;
  unsigned short* Kb = (unsigned short*)p;    p += SZ_T;
  unsigned short* Vt = (unsigned short*)p;    p += SZ_T;
  unsigned short* Ao = (unsigned short*)p;    p += SZ_T;

  cast_bf16_kernel<<<8192, 256, 0, stream>>>(hs, hs_bf, 8192 * 1024 / 4);
  transpose_cast_kernel<<<dim3(96, 32), 256, 0, stream>>>(W_attn, WtA, 1024, 3072);
  transpose_cast_kernel<<<dim3(32, 32), 256, 0, stream>>>(W_proj, WtP, 1024, 1024);
  gemm_kernel<0><<<1536, 256, 0, stream>>>(hs_bf, WtA, b_attn, nullptr, Qb, Kb, Vt,
                                           8192, 3072, 1024);
  attn_kernel<<<512, 512, 0, stream>>>(Qb, Kb, Vt, Ao);
  gemm_kernel<1><<<512, 256, 0, stream>>>(Ao, WtP, b_proj, out, nullptr, nullptr, nullptr,
                                          8192, 1024, 1024);
}

// Round 12
// 165.934 us; speedup vs baseline: 1.0982x; 1.0982x over previous
//
#include <hip/hip_runtime.h>
#include <stdint.h>

typedef __attribute__((ext_vector_type(8))) short short8;
typedef __attribute__((ext_vector_type(8))) __bf16 bf16x8v;
typedef __attribute__((ext_vector_type(4))) float f32x4;

#define GLOBAL_AS __attribute__((address_space(1)))
#define LDS_AS __attribute__((address_space(3)))

__device__ __forceinline__ void gl2lds16(const void* g, void* l) {
  __builtin_amdgcn_global_load_lds((const GLOBAL_AS void*)g, (LDS_AS void*)l, 16, 0, 0);
}

__device__ __forceinline__ unsigned short f2bf(float x) {
  unsigned int u = __builtin_bit_cast(unsigned int, x);
  return (unsigned short)((u + 0x7fffu + ((u >> 16) & 1u)) >> 16);
}

__device__ __forceinline__ float bf2f(unsigned short u) {
  unsigned int v = (unsigned int)u << 16;
  return __builtin_bit_cast(float, v);
}

__device__ __forceinline__ unsigned cvtpk(float lo, float hi) {
  unsigned r;
  asm volatile("v_cvt_pk_bf16_f32 %0, %1, %2" : "=v"(r) : "v"(lo), "v"(hi));
  return r;
}

// native 2^x — single v_exp_f32 (libm exp2f may expand to a guarded sequence)
__device__ __forceinline__ float fexp2(float x) {
  float r;
  asm volatile("v_exp_f32 %0, %1" : "=v"(r) : "v"(x));
  return r;
}

__device__ __forceinline__ short8 ldv8(const unsigned short* p) {
  return *(const short8*)p;
}

// --- MFMA wrapper: SFINAE-hedged against builtin operand type (short8 vs v8bf16) ---
template <typename T>
__device__ __forceinline__ auto mfma_impl(T a, T b, f32x4 c, int)
    -> decltype(__builtin_amdgcn_mfma_f32_16x16x32_bf16(a, b, c, 0, 0, 0)) {
  return __builtin_amdgcn_mfma_f32_16x16x32_bf16(a, b, c, 0, 0, 0);
}
template <typename T>
__device__ __forceinline__ f32x4 mfma_impl(T a, T b, f32x4 c, long) {
  bf16x8v aa = __builtin_bit_cast(bf16x8v, a);
  bf16x8v bb = __builtin_bit_cast(bf16x8v, b);
  return __builtin_amdgcn_mfma_f32_16x16x32_bf16(aa, bb, c, 0, 0, 0);
}
__device__ __forceinline__ f32x4 mfma16(short8 a, short8 b, f32x4 c) {
  return mfma_impl(a, b, c, 0);
}

// ---------------- cast fp32 -> bf16 (vectorized) ----------------
__global__ __launch_bounds__(256) void cast_bf16_kernel(const float* __restrict__ X,
                                                        unsigned short* __restrict__ Y,
                                                        int n4) {
  int i = blockIdx.x * 256 + threadIdx.x;
  if (i >= n4) return;
  const float4 v = ((const float4*)X)[i];
  unsigned long long pk = (unsigned long long)f2bf(v.x)
                        | ((unsigned long long)f2bf(v.y) << 16)
                        | ((unsigned long long)f2bf(v.z) << 32)
                        | ((unsigned long long)f2bf(v.w) << 48);
  ((unsigned long long*)Y)[i] = pk;
}

// ---------------- transpose + cast: W[K][N] fp32 -> Wt[N][K] bf16 ----------------
__global__ __launch_bounds__(256) void transpose_cast_kernel(const float* __restrict__ W,
                                                             unsigned short* __restrict__ Wt,
                                                             int Kd, int Nd) {
  __shared__ unsigned short tile[32][33];
  const int n0 = blockIdx.x * 32, k0 = blockIdx.y * 32;
  const int tx = threadIdx.x & 31, ty = threadIdx.x >> 5;  // 32x8
  #pragma unroll
  for (int i = 0; i < 4; ++i)
    tile[ty + i * 8][tx] = f2bf(W[(long)(k0 + ty + i * 8) * Nd + n0 + tx]);
  __syncthreads();
  #pragma unroll
  for (int i = 0; i < 4; ++i)
    Wt[(long)(n0 + ty + i * 8) * Kd + k0 + tx] = tile[tx][ty + i * 8];
}

// ---------------- GEMM: C[M,N] = A[M,K] @ Wt[N,K]^T + bias ----------------
// 128x128 tile, BK=32, TRIPLE-buffered with counted vmcnt(4).
// XCD-aware 1D block decode. MODE 0: QKV scatter; MODE 1: fp32 out.
template <int MODE>
__global__ __launch_bounds__(256, 3) void gemm_kernel(
    const unsigned short* __restrict__ A,   // [M][K] bf16
    const unsigned short* __restrict__ Wt,  // [N][K] bf16
    const float* __restrict__ bias,         // [N]
    float* __restrict__ Cout,               // MODE1
    unsigned short* __restrict__ Qb,
    unsigned short* __restrict__ Kb,
    unsigned short* __restrict__ Vt,
    int M, int N, int K) {
  __shared__ __align__(16) unsigned short Asm[3][128 * 32];
  __shared__ __align__(16) unsigned short Bsm[3][128 * 32];
  const int tid = threadIdx.x;
  const int w = tid >> 6, l = tid & 63;

  const int bid = blockIdx.x;
  const int xcd = bid & 7, tt = bid >> 3;
  int xb, yb;
  if (MODE == 0) {
    xb = (xcd & 1) * 12 + tt % 12;   // 24 n-blocks
    yb = (xcd >> 1) * 16 + tt / 12;  // 64 m-blocks
  } else {
    xb = tt & 7;                     // 8 n-blocks
    yb = xcd * 8 + (tt >> 3);        // 64 m-blocks
  }
  const int m0 = yb * 128, n0 = xb * 128;

  const int wr = (w >> 1) * 64, wc = (w & 1) * 64;
  const int laneRow = l & 15, laneG = l >> 4;

  const f32x4 z4 = {0.f, 0.f, 0.f, 0.f};
  f32x4 acc[4][4];
  #pragma unroll
  for (int m = 0; m < 4; ++m)
    #pragma unroll
    for (int n = 0; n < 4; ++n) acc[m][n] = z4;

  const int srow = tid >> 2;
  const int scol = (tid & 3) * 8;
  const unsigned short* Ag = A + (long)(m0 + srow) * K + scol;
  const unsigned short* Bg = Wt + (long)(n0 + srow) * K + scol;

  const int aoff = (wr + laneRow) * 32 + laneG * 8;
  const int boff = (wc + laneRow) * 32 + laneG * 8;

  auto STAGE = [&](int buf, int kt) {
    gl2lds16(Ag + kt, &Asm[buf][w * 512]);
    gl2lds16(Ag + (long)64 * K + kt, &Asm[buf][2048 + w * 512]);
    gl2lds16(Bg + kt, &Bsm[buf][w * 512]);
    gl2lds16(Bg + (long)64 * K + kt, &Bsm[buf][2048 + w * 512]);
  };

  const int NT = K >> 5;
  STAGE(0, 0);
  STAGE(1, 32);
  asm volatile("s_waitcnt vmcnt(4)" ::: "memory");  // tile0 ready; tile1 in flight
  asm volatile("s_barrier" ::: "memory");

  int cur = 0, sb = 2;
  for (int t = 0; t < NT; ++t) {
    if (t + 2 < NT) STAGE(sb, (t + 2) * 32);
    short8 af[4], bfr[4];
    #pragma unroll
    for (int m = 0; m < 4; ++m) af[m] = ldv8(&Asm[cur][aoff + m * 512]);
    #pragma unroll
    for (int n = 0; n < 4; ++n) bfr[n] = ldv8(&Bsm[cur][boff + n * 512]);
    __builtin_amdgcn_s_setprio(1);
    #pragma unroll
    for (int m = 0; m < 4; ++m)
      #pragma unroll
      for (int n = 0; n < 4; ++n)
        acc[m][n] = mfma16(af[m], bfr[n], acc[m][n]);
    __builtin_amdgcn_s_setprio(0);
    if (t + 2 < NT) {
      asm volatile("s_waitcnt vmcnt(4)" ::: "memory");
    } else {
      asm volatile("s_waitcnt vmcnt(0)" ::: "memory");
    }
    asm volatile("s_barrier" ::: "memory");
    cur = (cur == 2) ? 0 : cur + 1;
    sb = (sb == 2) ? 0 : sb + 1;
  }

  if (MODE == 0 && n0 >= 2048) {
    #pragma unroll
    for (int m = 0; m < 4; ++m) {
      const int row_base = m0 + wr + m * 16 + laneG * 4;
      #pragma unroll
      for (int n = 0; n < 4; ++n) {
        const int col = n0 + wc + n * 16 + laneRow;
        const float bv = bias[col];
        const int d = col & 1023;
        const int h = d >> 6, e = d & 63;
        const int bb = row_base >> 11, s = row_base & 2047;
        unsigned long long pk = (unsigned long long)f2bf(acc[m][n][0] + bv)
                              | ((unsigned long long)f2bf(acc[m][n][1] + bv) << 16)
                              | ((unsigned long long)f2bf(acc[m][n][2] + bv) << 32)
                              | ((unsigned long long)f2bf(acc[m][n][3] + bv) << 48);
        *(unsigned long long*)(Vt + ((long)((bb * 16 + h) * 64 + e)) * 2048 + s) = pk;
      }
    }
    return;
  }

  // LDS-bounce epilogue: per-wave 16x68 f32 region, coalesced 16B stores
  float* ep = (float*)&Asm[0][0] + w * 1088;
  const int c0 = (l & 7) * 8;
  const int rrow = l >> 3;
  const int colg0 = n0 + wc + c0;
  float bv[8];
  #pragma unroll
  for (int j = 0; j < 8; ++j) bv[j] = bias[colg0 + j];
  unsigned short* Tqk = (colg0 >> 10) ? Kb : Qb;
  const int hh = (colg0 & 1023) >> 6, e0 = colg0 & 63;

  #pragma unroll
  for (int m = 0; m < 4; ++m) {
    asm volatile("s_waitcnt lgkmcnt(0)" ::: "memory");
    #pragma unroll
    for (int n = 0; n < 4; ++n)
      #pragma unroll
      for (int r = 0; r < 4; ++r)
        ep[(laneG * 4 + r) * 68 + n * 16 + laneRow] = acc[m][n][r];
    asm volatile("s_waitcnt lgkmcnt(0)" ::: "memory");
    #pragma unroll
    for (int j = 0; j < 2; ++j) {
      const int row = rrow + j * 8;
      f32x4 va = *(const f32x4*)&ep[row * 68 + c0];
      f32x4 vb = *(const f32x4*)&ep[row * 68 + c0 + 4];
      va[0] += bv[0]; va[1] += bv[1]; va[2] += bv[2]; va[3] += bv[3];
      vb[0] += bv[4]; vb[1] += bv[5]; vb[2] += bv[6]; vb[3] += bv[7];
      const int row_g = m0 + wr + m * 16 + row;
      if (MODE == 1) {
        *(f32x4*)&Cout[(long)row_g * N + colg0] = va;
        *(f32x4*)&Cout[(long)row_g * N + colg0 + 4] = vb;
      } else {
        uint4 pk;
        pk.x = cvtpk(va[0], va[1]);
        pk.y = cvtpk(va[2], va[3]);
        pk.z = cvtpk(vb[0], vb[1]);
        pk.w = cvtpk(vb[2], vb[3]);
        const int bb = row_g >> 11, s = row_g & 2047;
        *(uint4*)(Tqk + ((long)(bb * 16 + hh) * 2048 + s) * 64 + e0) = pk;
      }
    }
  }
}

// ---------------- flash attention (causal), bf16 MFMA ----------------
// QBLK=128, 8 waves. Paired tiles px/(15-px), XCD-aware head grouping.
// SWAPPED QK^T -> S^T per lane; P via cvt_pk + b64 writes; no max-shift;
// P = 2^S via single v_exp_f32 (native exp2). Rowsum via mfma(P, ones).
// TRIPLE-buffered K/V with counted vmcnt(2).
__global__ __launch_bounds__(512) void attn_kernel(
    const unsigned short* __restrict__ Qb,   // [B*H][2048][64]
    const unsigned short* __restrict__ Kb,   // [B*H][2048][64]
    const unsigned short* __restrict__ Vt,   // [B*H][64][2048]
    unsigned short* __restrict__ Ao) {       // [B*2048][1024]
  __shared__ __align__(16) unsigned short Ksm[3][64 * 64];
  __shared__ __align__(16) unsigned short Vsm[3][64 * 64];
  __shared__ __align__(16) unsigned short Psm[8][16][72];

  const int tid = threadIdx.x;
  const int w = tid >> 6, l = tid & 63;
  const int bid = blockIdx.x;
  const int px = bid >> 6;                              // 0..7
  const int y = ((bid & 7) << 3) | ((bid >> 3) & 7);    // same-XCD head grouping
  const int laneRow = l & 15, g = l >> 4;
  const unsigned short* Qh = Qb + (long)y * (2048 * 64);
  const unsigned short* Kh = Kb + (long)y * (2048 * 64);
  const unsigned short* Vh = Vt + (long)y * (64 * 2048);

  const int srow = tid >> 3;
  const int sxor = ((tid & 7) ^ (srow & 7)) * 8;
  const int b = y >> 4, h = y & 15;
  const f32x4 z4 = {0.f, 0.f, 0.f, 0.f};
  short8 ones8;
  #pragma unroll
  for (int j = 0; j < 8; ++j) ones8[j] = (short)0x3F80;

  auto STAGE = [&](int buf, int kt) {
    gl2lds16(Kh + (long)kt * 4096 + srow * 64 + sxor, &Ksm[buf][w * 512]);
    gl2lds16(Vh + kt * 64 + (long)srow * 2048 + sxor, &Vsm[buf][w * 512]);
  };

  for (int pass = 0; pass < 2; ++pass) {
    const int x = pass ? (15 - px) : px;
    const int q0 = x * 128;
    const int qlo = w * 16;

    const float QS = 0.18033688011112042f;
    short8 qf[2];
    {
      short8 r0 = ldv8(Qh + (q0 + qlo + laneRow) * 64 + g * 8);
      short8 r1 = ldv8(Qh + (q0 + qlo + laneRow) * 64 + 32 + g * 8);
      #pragma unroll
      for (int j = 0; j < 8; ++j) {
        qf[0][j] = (short)f2bf(bf2f((unsigned short)r0[j]) * QS);
        qf[1][j] = (short)f2bf(bf2f((unsigned short)r1[j]) * QS);
      }
    }

    float lr[4] = {0.f, 0.f, 0.f, 0.f};
    f32x4 o[4];
    #pragma unroll
    for (int i = 0; i < 4; ++i) o[i] = z4;

    const int nkt = 2 * x + 2;  // always >= 2
    STAGE(0, 0);
    STAGE(1, 1);
    asm volatile("s_waitcnt vmcnt(2)" ::: "memory");  // tile0 ready; tile1 in flight
    __builtin_amdgcn_s_barrier();

    int cur = 0, sb = 2;
    for (int kt = 0; kt < nkt; ++kt) {
      if (kt + 2 < nkt) STAGE(sb, kt + 2);

      const int keybase = kt * 64 - q0;
      const bool fullskip = keybase > qlo + 15;

      if (!fullskip) {
        f32x4 sc[4];
        __builtin_amdgcn_s_setprio(1);
        #pragma unroll
        for (int n = 0; n < 4; ++n) {
          const int krow = n * 16 + laneRow;
          short8 b0 = ldv8(&Ksm[cur][krow * 64 + ((g ^ (krow & 7)) * 8)]);
          short8 b1 = ldv8(&Ksm[cur][krow * 64 + (((g + 4) ^ (krow & 7)) * 8)]);
          f32x4 a = mfma16(b0, qf[0], z4);
          sc[n] = mfma16(b1, qf[1], a);
        }
        __builtin_amdgcn_s_setprio(0);

        if (keybase + 63 > qlo) {
          #pragma unroll
          for (int n = 0; n < 4; ++n) {
            const int keyb = keybase + n * 16 + g * 4;
            #pragma unroll
            for (int r = 0; r < 4; ++r)
              if (keyb + r > qlo + laneRow) sc[n][r] = -1e9f;
          }
        }

        #pragma unroll
        for (int n = 0; n < 4; ++n)
          #pragma unroll
          for (int r = 0; r < 4; ++r)
            sc[n][r] = fexp2(sc[n][r]);

        #pragma unroll
        for (int n = 0; n < 4; ++n) {
          uint2 pk;
          pk.x = cvtpk(sc[n][0], sc[n][1]);
          pk.y = cvtpk(sc[n][2], sc[n][3]);
          *(uint2*)&Psm[w][laneRow][n * 16 + g * 4] = pk;
        }
        asm volatile("s_waitcnt lgkmcnt(0)" ::: "memory");

        f32x4 rs = z4;
        #pragma unroll
        for (int kk = 0; kk < 2; ++kk) {
          short8 pf = ldv8(&Psm[w][laneRow][kk * 32 + g * 8]);
          __builtin_amdgcn_s_setprio(1);
          #pragma unroll
          for (int n2 = 0; n2 < 4; ++n2) {
            const int vrow = n2 * 16 + laneRow;
            short8 vf = ldv8(&Vsm[cur][vrow * 64 + (((g + kk * 4) ^ (vrow & 7)) * 8)]);
            o[n2] = mfma16(pf, vf, o[n2]);
          }
          rs = mfma16(pf, ones8, rs);
          __builtin_amdgcn_s_setprio(0);
        }
        #pragma unroll
        for (int r = 0; r < 4; ++r) lr[r] += rs[r];
      }

      // boundary: tile kt+1 must be resident; kt+2's loads stay in flight
      if (kt + 2 < nkt) {
        asm volatile("s_waitcnt vmcnt(2)" ::: "memory");
      } else {
        asm volatile("s_waitcnt vmcnt(0)" ::: "memory");
      }
      __builtin_amdgcn_s_barrier();
      cur = (cur == 2) ? 0 : cur + 1;
      sb = (sb == 2) ? 0 : sb + 1;
    }

    #pragma unroll
    for (int n2 = 0; n2 < 4; ++n2) {
      #pragma unroll
      for (int r = 0; r < 4; ++r) {
        float v = o[n2][r] / lr[r];
        long row = (long)b * 2048 + q0 + qlo + g * 4 + r;
        Ao[row * 1024 + h * 64 + n2 * 16 + laneRow] = f2bf(v);
      }
    }
  }
}

// ---------------- launch ----------------
extern "C" void kernel_launch(void* const* d_in, const int* in_sizes, int n_in,
                              void* d_out, int out_size, void* d_ws, size_t ws_size,
                              hipStream_t stream) {
  const float* hs = (const float*)d_in[0];      // [4,2048,1024]
  const float* W_attn = (const float*)d_in[1];  // [1024,3072]
  const float* b_attn = (const float*)d_in[2];  // [3072]
  const float* W_proj = (const float*)d_in[3];  // [1024,1024]
  const float* b_proj = (const float*)d_in[4];  // [1024]
  float* out = (float*)d_out;

  const size_t SZ_HS = 16777216;  // 8192*1024*2
  const size_t SZ_WA = 6291456;   // 3072*1024*2
  const size_t SZ_WP = 2097152;   // 1024*1024*2
  const size_t SZ_T = 16777216;   // Q / K / Vt / Ao each
  if (ws_size < SZ_HS + SZ_WA + SZ_WP + 4 * SZ_T) return;

  char* p = (char*)d_ws;
  unsigned short* hs_bf = (unsigned short*)p; p += SZ_HS;
  unsigned short* WtA = (unsigned short*)p;   p += SZ_WA;
  unsigned short* WtP = (unsigned short*)p;   p += SZ_WP;
  unsigned short* Qb = (unsigned short*)p;    p += SZ_T;
  unsigned short* Kb = (unsigned short*)p;    p += SZ_T;
  unsigned short* Vt = (unsigned short*)p;    p += SZ_T;
  unsigned short* Ao = (unsigned short*)p;    p += SZ_T;

  cast_bf16_kernel<<<8192, 256, 0, stream>>>(hs, hs_bf, 8192 * 1024 / 4);
  transpose_cast_kernel<<<dim3(96, 32), 256, 0, stream>>>(W_attn, WtA, 1024, 3072);
  transpose_cast_kernel<<<dim3(32, 32), 256, 0, stream>>>(W_proj, WtP, 1024, 1024);
  gemm_kernel<0><<<1536, 256, 0, stream>>>(hs_bf, WtA, b_attn, nullptr, Qb, Kb, Vt,
                                           8192, 3072, 1024);
  attn_kernel<<<512, 512, 0, stream>>>(Qb, Kb, Vt, Ao);
  gemm_kernel<1><<<512, 256, 0, stream>>>(Ao, WtP, b_proj, out, nullptr, nullptr, nullptr,
                                          8192, 1024, 1024);
}

// Round 13
// 165.807 us; speedup vs baseline: 1.0991x; 1.0008x over previous
//
#include <hip/hip_runtime.h>
#include <stdint.h>

typedef __attribute__((ext_vector_type(8))) short short8;
typedef __attribute__((ext_vector_type(8))) __bf16 bf16x8v;
typedef __attribute__((ext_vector_type(4))) float f32x4;

#define GLOBAL_AS __attribute__((address_space(1)))
#define LDS_AS __attribute__((address_space(3)))

__device__ __forceinline__ void gl2lds16(const void* g, void* l) {
  __builtin_amdgcn_global_load_lds((const GLOBAL_AS void*)g, (LDS_AS void*)l, 16, 0, 0);
}

__device__ __forceinline__ unsigned short f2bf(float x) {
  unsigned int u = __builtin_bit_cast(unsigned int, x);
  return (unsigned short)((u + 0x7fffu + ((u >> 16) & 1u)) >> 16);
}

__device__ __forceinline__ float bf2f(unsigned short u) {
  unsigned int v = (unsigned int)u << 16;
  return __builtin_bit_cast(float, v);
}

__device__ __forceinline__ unsigned cvtpk(float lo, float hi) {
  unsigned r;
  asm volatile("v_cvt_pk_bf16_f32 %0, %1, %2" : "=v"(r) : "v"(lo), "v"(hi));
  return r;
}

// native 2^x — single v_exp_f32 (libm exp2f may expand to a guarded sequence)
__device__ __forceinline__ float fexp2(float x) {
  float r;
  asm volatile("v_exp_f32 %0, %1" : "=v"(r) : "v"(x));
  return r;
}

__device__ __forceinline__ short8 ldv8(const unsigned short* p) {
  return *(const short8*)p;
}

// --- MFMA wrapper: SFINAE-hedged against builtin operand type (short8 vs v8bf16) ---
template <typename T>
__device__ __forceinline__ auto mfma_impl(T a, T b, f32x4 c, int)
    -> decltype(__builtin_amdgcn_mfma_f32_16x16x32_bf16(a, b, c, 0, 0, 0)) {
  return __builtin_amdgcn_mfma_f32_16x16x32_bf16(a, b, c, 0, 0, 0);
}
template <typename T>
__device__ __forceinline__ f32x4 mfma_impl(T a, T b, f32x4 c, long) {
  bf16x8v aa = __builtin_bit_cast(bf16x8v, a);
  bf16x8v bb = __builtin_bit_cast(bf16x8v, b);
  return __builtin_amdgcn_mfma_f32_16x16x32_bf16(aa, bb, c, 0, 0, 0);
}
__device__ __forceinline__ f32x4 mfma16(short8 a, short8 b, f32x4 c) {
  return mfma_impl(a, b, c, 0);
}

// ---------------- cast fp32 -> bf16 (vectorized) ----------------
__global__ __launch_bounds__(256) void cast_bf16_kernel(const float* __restrict__ X,
                                                        unsigned short* __restrict__ Y,
                                                        int n4) {
  int i = blockIdx.x * 256 + threadIdx.x;
  if (i >= n4) return;
  const float4 v = ((const float4*)X)[i];
  unsigned long long pk = (unsigned long long)f2bf(v.x)
                        | ((unsigned long long)f2bf(v.y) << 16)
                        | ((unsigned long long)f2bf(v.z) << 32)
                        | ((unsigned long long)f2bf(v.w) << 48);
  ((unsigned long long*)Y)[i] = pk;
}

// ---------------- transpose + cast: W[K][N] fp32 -> Wt[N][K] bf16 ----------------
__global__ __launch_bounds__(256) void transpose_cast_kernel(const float* __restrict__ W,
                                                             unsigned short* __restrict__ Wt,
                                                             int Kd, int Nd) {
  __shared__ unsigned short tile[32][33];
  const int n0 = blockIdx.x * 32, k0 = blockIdx.y * 32;
  const int tx = threadIdx.x & 31, ty = threadIdx.x >> 5;  // 32x8
  #pragma unroll
  for (int i = 0; i < 4; ++i)
    tile[ty + i * 8][tx] = f2bf(W[(long)(k0 + ty + i * 8) * Nd + n0 + tx]);
  __syncthreads();
  #pragma unroll
  for (int i = 0; i < 4; ++i)
    Wt[(long)(n0 + ty + i * 8) * Kd + k0 + tx] = tile[tx][ty + i * 8];
}

// ---------------- GEMM: C[M,N] = A[M,K] @ Wt[N,K]^T + bias ----------------
// 128x128 tile, BK=32, TRIPLE-buffered with counted vmcnt(4).
// T2 XOR-swizzle: LDS [128][32] tiles staged with pre-swizzled GLOBAL source
// col ((tid&3)^(srow&3)) + linear gl2lds dest; fragment reads at slot
// laneG^(laneRow&3). 8-way bank conflict -> 4-way.
// XCD-aware 1D block decode. MODE 0: QKV scatter; MODE 1: fp32 out.
template <int MODE>
__global__ __launch_bounds__(256, 3) void gemm_kernel(
    const unsigned short* __restrict__ A,   // [M][K] bf16
    const unsigned short* __restrict__ Wt,  // [N][K] bf16
    const float* __restrict__ bias,         // [N]
    float* __restrict__ Cout,               // MODE1
    unsigned short* __restrict__ Qb,
    unsigned short* __restrict__ Kb,
    unsigned short* __restrict__ Vt,
    int M, int N, int K) {
  __shared__ __align__(16) unsigned short Asm[3][128 * 32];
  __shared__ __align__(16) unsigned short Bsm[3][128 * 32];
  const int tid = threadIdx.x;
  const int w = tid >> 6, l = tid & 63;

  const int bid = blockIdx.x;
  const int xcd = bid & 7, tt = bid >> 3;
  int xb, yb;
  if (MODE == 0) {
    xb = (xcd & 1) * 12 + tt % 12;   // 24 n-blocks
    yb = (xcd >> 1) * 16 + tt / 12;  // 64 m-blocks
  } else {
    xb = tt & 7;                     // 8 n-blocks
    yb = xcd * 8 + (tt >> 3);        // 64 m-blocks
  }
  const int m0 = yb * 128, n0 = xb * 128;

  const int wr = (w >> 1) * 64, wc = (w & 1) * 64;
  const int laneRow = l & 15, laneG = l >> 4;

  const f32x4 z4 = {0.f, 0.f, 0.f, 0.f};
  f32x4 acc[4][4];
  #pragma unroll
  for (int m = 0; m < 4; ++m)
    #pragma unroll
    for (int n = 0; n < 4; ++n) acc[m][n] = z4;

  const int srow = tid >> 2;
  // T2: pre-swizzled global source col (linear LDS dest, swizzled read)
  const int scol = ((tid & 3) ^ (srow & 3)) * 8;
  const unsigned short* Ag = A + (long)(m0 + srow) * K + scol;
  const unsigned short* Bg = Wt + (long)(n0 + srow) * K + scol;

  const int aoff = (wr + laneRow) * 32 + (laneG ^ (laneRow & 3)) * 8;
  const int boff = (wc + laneRow) * 32 + (laneG ^ (laneRow & 3)) * 8;

  auto STAGE = [&](int buf, int kt) {
    gl2lds16(Ag + kt, &Asm[buf][w * 512]);
    gl2lds16(Ag + (long)64 * K + kt, &Asm[buf][2048 + w * 512]);
    gl2lds16(Bg + kt, &Bsm[buf][w * 512]);
    gl2lds16(Bg + (long)64 * K + kt, &Bsm[buf][2048 + w * 512]);
  };

  const int NT = K >> 5;
  STAGE(0, 0);
  STAGE(1, 32);
  asm volatile("s_waitcnt vmcnt(4)" ::: "memory");  // tile0 ready; tile1 in flight
  asm volatile("s_barrier" ::: "memory");

  int cur = 0, sb = 2;
  for (int t = 0; t < NT; ++t) {
    if (t + 2 < NT) STAGE(sb, (t + 2) * 32);
    short8 af[4], bfr[4];
    #pragma unroll
    for (int m = 0; m < 4; ++m) af[m] = ldv8(&Asm[cur][aoff + m * 512]);
    #pragma unroll
    for (int n = 0; n < 4; ++n) bfr[n] = ldv8(&Bsm[cur][boff + n * 512]);
    __builtin_amdgcn_s_setprio(1);
    #pragma unroll
    for (int m = 0; m < 4; ++m)
      #pragma unroll
      for (int n = 0; n < 4; ++n)
        acc[m][n] = mfma16(af[m], bfr[n], acc[m][n]);
    __builtin_amdgcn_s_setprio(0);
    if (t + 2 < NT) {
      asm volatile("s_waitcnt vmcnt(4)" ::: "memory");
    } else {
      asm volatile("s_waitcnt vmcnt(0)" ::: "memory");
    }
    asm volatile("s_barrier" ::: "memory");
    cur = (cur == 2) ? 0 : cur + 1;
    sb = (sb == 2) ? 0 : sb + 1;
  }

  if (MODE == 0 && n0 >= 2048) {
    #pragma unroll
    for (int m = 0; m < 4; ++m) {
      const int row_base = m0 + wr + m * 16 + laneG * 4;
      #pragma unroll
      for (int n = 0; n < 4; ++n) {
        const int col = n0 + wc + n * 16 + laneRow;
        const float bv = bias[col];
        const int d = col & 1023;
        const int h = d >> 6, e = d & 63;
        const int bb = row_base >> 11, s = row_base & 2047;
        unsigned long long pk = (unsigned long long)f2bf(acc[m][n][0] + bv)
                              | ((unsigned long long)f2bf(acc[m][n][1] + bv) << 16)
                              | ((unsigned long long)f2bf(acc[m][n][2] + bv) << 32)
                              | ((unsigned long long)f2bf(acc[m][n][3] + bv) << 48);
        *(unsigned long long*)(Vt + ((long)((bb * 16 + h) * 64 + e)) * 2048 + s) = pk;
      }
    }
    return;
  }

  // LDS-bounce epilogue: per-wave 16x68 f32 region, coalesced 16B stores
  float* ep = (float*)&Asm[0][0] + w * 1088;
  const int c0 = (l & 7) * 8;
  const int rrow = l >> 3;
  const int colg0 = n0 + wc + c0;
  float bv[8];
  #pragma unroll
  for (int j = 0; j < 8; ++j) bv[j] = bias[colg0 + j];
  unsigned short* Tqk = (colg0 >> 10) ? Kb : Qb;
  const int hh = (colg0 & 1023) >> 6, e0 = colg0 & 63;

  #pragma unroll
  for (int m = 0; m < 4; ++m) {
    asm volatile("s_waitcnt lgkmcnt(0)" ::: "memory");
    #pragma unroll
    for (int n = 0; n < 4; ++n)
      #pragma unroll
      for (int r = 0; r < 4; ++r)
        ep[(laneG * 4 + r) * 68 + n * 16 + laneRow] = acc[m][n][r];
    asm volatile("s_waitcnt lgkmcnt(0)" ::: "memory");
    #pragma unroll
    for (int j = 0; j < 2; ++j) {
      const int row = rrow + j * 8;
      f32x4 va = *(const f32x4*)&ep[row * 68 + c0];
      f32x4 vb = *(const f32x4*)&ep[row * 68 + c0 + 4];
      va[0] += bv[0]; va[1] += bv[1]; va[2] += bv[2]; va[3] += bv[3];
      vb[0] += bv[4]; vb[1] += bv[5]; vb[2] += bv[6]; vb[3] += bv[7];
      const int row_g = m0 + wr + m * 16 + row;
      if (MODE == 1) {
        *(f32x4*)&Cout[(long)row_g * N + colg0] = va;
        *(f32x4*)&Cout[(long)row_g * N + colg0 + 4] = vb;
      } else {
        uint4 pk;
        pk.x = cvtpk(va[0], va[1]);
        pk.y = cvtpk(va[2], va[3]);
        pk.z = cvtpk(vb[0], vb[1]);
        pk.w = cvtpk(vb[2], vb[3]);
        const int bb = row_g >> 11, s = row_g & 2047;
        *(uint4*)(Tqk + ((long)(bb * 16 + hh) * 2048 + s) * 64 + e0) = pk;
      }
    }
  }
}

// ---------------- flash attention (causal), bf16 MFMA ----------------
// QBLK=128, 8 waves. Paired tiles px/(15-px), XCD-aware head grouping.
// SWAPPED QK^T -> S^T per lane; P via cvt_pk + b64 writes; no max-shift;
// P = 2^S via single v_exp_f32 (native exp2). Rowsum via mfma(P, ones).
// TRIPLE-buffered K/V with counted vmcnt(2).
__global__ __launch_bounds__(512) void attn_kernel(
    const unsigned short* __restrict__ Qb,   // [B*H][2048][64]
    const unsigned short* __restrict__ Kb,   // [B*H][2048][64]
    const unsigned short* __restrict__ Vt,   // [B*H][64][2048]
    unsigned short* __restrict__ Ao) {       // [B*2048][1024]
  __shared__ __align__(16) unsigned short Ksm[3][64 * 64];
  __shared__ __align__(16) unsigned short Vsm[3][64 * 64];
  __shared__ __align__(16) unsigned short Psm[8][16][72];

  const int tid = threadIdx.x;
  const int w = tid >> 6, l = tid & 63;
  const int bid = blockIdx.x;
  const int px = bid >> 6;                              // 0..7
  const int y = ((bid & 7) << 3) | ((bid >> 3) & 7);    // same-XCD head grouping
  const int laneRow = l & 15, g = l >> 4;
  const unsigned short* Qh = Qb + (long)y * (2048 * 64);
  const unsigned short* Kh = Kb + (long)y * (2048 * 64);
  const unsigned short* Vh = Vt + (long)y * (64 * 2048);

  const int srow = tid >> 3;
  const int sxor = ((tid & 7) ^ (srow & 7)) * 8;
  const int b = y >> 4, h = y & 15;
  const f32x4 z4 = {0.f, 0.f, 0.f, 0.f};
  short8 ones8;
  #pragma unroll
  for (int j = 0; j < 8; ++j) ones8[j] = (short)0x3F80;

  auto STAGE = [&](int buf, int kt) {
    gl2lds16(Kh + (long)kt * 4096 + srow * 64 + sxor, &Ksm[buf][w * 512]);
    gl2lds16(Vh + kt * 64 + (long)srow * 2048 + sxor, &Vsm[buf][w * 512]);
  };

  for (int pass = 0; pass < 2; ++pass) {
    const int x = pass ? (15 - px) : px;
    const int q0 = x * 128;
    const int qlo = w * 16;

    const float QS = 0.18033688011112042f;
    short8 qf[2];
    {
      short8 r0 = ldv8(Qh + (q0 + qlo + laneRow) * 64 + g * 8);
      short8 r1 = ldv8(Qh + (q0 + qlo + laneRow) * 64 + 32 + g * 8);
      #pragma unroll
      for (int j = 0; j < 8; ++j) {
        qf[0][j] = (short)f2bf(bf2f((unsigned short)r0[j]) * QS);
        qf[1][j] = (short)f2bf(bf2f((unsigned short)r1[j]) * QS);
      }
    }

    float lr[4] = {0.f, 0.f, 0.f, 0.f};
    f32x4 o[4];
    #pragma unroll
    for (int i = 0; i < 4; ++i) o[i] = z4;

    const int nkt = 2 * x + 2;  // always >= 2
    STAGE(0, 0);
    STAGE(1, 1);
    asm volatile("s_waitcnt vmcnt(2)" ::: "memory");  // tile0 ready; tile1 in flight
    __builtin_amdgcn_s_barrier();

    int cur = 0, sb = 2;
    for (int kt = 0; kt < nkt; ++kt) {
      if (kt + 2 < nkt) STAGE(sb, kt + 2);

      const int keybase = kt * 64 - q0;
      const bool fullskip = keybase > qlo + 15;

      if (!fullskip) {
        f32x4 sc[4];
        __builtin_amdgcn_s_setprio(1);
        #pragma unroll
        for (int n = 0; n < 4; ++n) {
          const int krow = n * 16 + laneRow;
          short8 b0 = ldv8(&Ksm[cur][krow * 64 + ((g ^ (krow & 7)) * 8)]);
          short8 b1 = ldv8(&Ksm[cur][krow * 64 + (((g + 4) ^ (krow & 7)) * 8)]);
          f32x4 a = mfma16(b0, qf[0], z4);
          sc[n] = mfma16(b1, qf[1], a);
        }
        __builtin_amdgcn_s_setprio(0);

        if (keybase + 63 > qlo) {
          #pragma unroll
          for (int n = 0; n < 4; ++n) {
            const int keyb = keybase + n * 16 + g * 4;
            #pragma unroll
            for (int r = 0; r < 4; ++r)
              if (keyb + r > qlo + laneRow) sc[n][r] = -1e9f;
          }
        }

        #pragma unroll
        for (int n = 0; n < 4; ++n)
          #pragma unroll
          for (int r = 0; r < 4; ++r)
            sc[n][r] = fexp2(sc[n][r]);

        #pragma unroll
        for (int n = 0; n < 4; ++n) {
          uint2 pk;
          pk.x = cvtpk(sc[n][0], sc[n][1]);
          pk.y = cvtpk(sc[n][2], sc[n][3]);
          *(uint2*)&Psm[w][laneRow][n * 16 + g * 4] = pk;
        }
        asm volatile("s_waitcnt lgkmcnt(0)" ::: "memory");

        f32x4 rs = z4;
        #pragma unroll
        for (int kk = 0; kk < 2; ++kk) {
          short8 pf = ldv8(&Psm[w][laneRow][kk * 32 + g * 8]);
          __builtin_amdgcn_s_setprio(1);
          #pragma unroll
          for (int n2 = 0; n2 < 4; ++n2) {
            const int vrow = n2 * 16 + laneRow;
            short8 vf = ldv8(&Vsm[cur][vrow * 64 + (((g + kk * 4) ^ (vrow & 7)) * 8)]);
            o[n2] = mfma16(pf, vf, o[n2]);
          }
          rs = mfma16(pf, ones8, rs);
          __builtin_amdgcn_s_setprio(0);
        }
        #pragma unroll
        for (int r = 0; r < 4; ++r) lr[r] += rs[r];
      }

      // boundary: tile kt+1 must be resident; kt+2's loads stay in flight
      if (kt + 2 < nkt) {
        asm volatile("s_waitcnt vmcnt(2)" ::: "memory");
      } else {
        asm volatile("s_waitcnt vmcnt(0)" ::: "memory");
      }
      __builtin_amdgcn_s_barrier();
      cur = (cur == 2) ? 0 : cur + 1;
      sb = (sb == 2) ? 0 : sb + 1;
    }

    #pragma unroll
    for (int n2 = 0; n2 < 4; ++n2) {
      #pragma unroll
      for (int r = 0; r < 4; ++r) {
        float v = o[n2][r] / lr[r];
        long row = (long)b * 2048 + q0 + qlo + g * 4 + r;
        Ao[row * 1024 + h * 64 + n2 * 16 + laneRow] = f2bf(v);
      }
    }
  }
}

// ---------------- launch ----------------
extern "C" void kernel_launch(void* const* d_in, const int* in_sizes, int n_in,
                              void* d_out, int out_size, void* d_ws, size_t ws_size,
                              hipStream_t stream) {
  const float* hs = (const float*)d_in[0];      // [4,2048,1024]
  const float* W_attn = (const float*)d_in[1];  // [1024,3072]
  const float* b_attn = (const float*)d_in[2];  // [3072]
  const float* W_proj = (const float*)d_in[3];  // [1024,1024]
  const float* b_proj = (const float*)d_in[4];  // [1024]
  float* out = (float*)d_out;

  const size_t SZ_HS = 16777216;  // 8192*1024*2
  const size_t SZ_WA = 6291456;   // 3072*1024*2
  const size_t SZ_WP = 2097152;   // 1024*1024*2
  const size_t SZ_T = 16777216;   // Q / K / Vt / Ao each
  if (ws_size < SZ_HS + SZ_WA + SZ_WP + 4 * SZ_T) return;

  char* p = (char*)d_ws;
  unsigned short* hs_bf = (unsigned short*)p; p += SZ_HS;
  unsigned short* WtA = (unsigned short*)p;   p += SZ_WA;
  unsigned short* WtP = (unsigned short*)p;   p += SZ_WP;
  unsigned short* Qb = (unsigned short*)p;    p += SZ_T;
  unsigned short* Kb = (unsigned short*)p;    p += SZ_T;
  unsigned short* Vt = (unsigned short*)p;    p += SZ_T;
  unsigned short* Ao = (unsigned short*)p;    p += SZ_T;

  cast_bf16_kernel<<<8192, 256, 0, stream>>>(hs, hs_bf, 8192 * 1024 / 4);
  transpose_cast_kernel<<<dim3(96, 32), 256, 0, stream>>>(W_attn, WtA, 1024, 3072);
  transpose_cast_kernel<<<dim3(32, 32), 256, 0, stream>>>(W_proj, WtP, 1024, 1024);
  gemm_kernel<0><<<1536, 256, 0, stream>>>(hs_bf, WtA, b_attn, nullptr, Qb, Kb, Vt,
                                           8192, 3072, 1024);
  attn_kernel<<<512, 512, 0, stream>>>(Qb, Kb, Vt, Ao);
  gemm_kernel<1><<<512, 256, 0, stream>>>(Ao, WtP, b_proj, out, nullptr, nullptr, nullptr,
                                          8192, 1024, 1024);
}